// Round 9
// baseline (157.748 us; speedup 1.0000x reference)
//
#include <hip/hip_runtime.h>
#include <hip/hip_bf16.h>

#define NB    128
#define NSIG  12
#define KLEN  4096
#define NF    2049          // rfft bins
#define NFP   2080          // padded (65*32)
#define NTAU  257
#define NROW  (NB*NSIG)
#define NSLICE 65           // K slices of 32
#define BROWS 144           // B tile rows (taus 0..128 live, 129..143 zero)
#define TBLN  (NSLICE*BROWS*32)   // shorts per phase table
#define OUT_ELEMS (NB*144*NTAU)

// k_corr dynamic LDS layout (shorts): Xs[3][1024] | Bs[3][9216] | As[2][1920]
#define XS_OFF 0
#define BS_OFF (3*1024)
#define AS_OFF (BS_OFF + 3*9216)
#define LDS_SHORTS (AS_OFF + 2*1920)

// LDS float address map: spreads stride-64 gathers across all 32 banks
#define AP(p) ((p) + ((p) >> 6))

typedef short short8_t __attribute__((ext_vector_type(8)));
typedef float floatx4  __attribute__((ext_vector_type(4)));

__device__ __forceinline__ unsigned short f2bf(float f) {
  union { float f; unsigned u; } v; v.f = f;
  unsigned r = v.u + 0x7FFFu + ((v.u >> 16) & 1u);   // RNE
  return (unsigned short)(r >> 16);
}
__device__ __forceinline__ float ubits(unsigned u) {
  union { unsigned u; float f; } v; v.u = u; return v.f;
}

// async global(16B) -> LDS; dest = wave-uniform base + lane*16
__device__ __forceinline__ void gload16(const unsigned short* g, unsigned short* l) {
  __builtin_amdgcn_global_load_lds((const __attribute__((address_space(1))) unsigned int*)g,
                                   (__attribute__((address_space(3))) unsigned int*)l, 16, 0, 0);
}

// base-4 digit reverse of a 12-bit index
__device__ __forceinline__ int dr4(int f) {
  unsigned rb = __brev((unsigned)f) >> 20;
  return (int)(((rb & 0x555u) << 1) | ((rb >> 1) & 0x555u));
}

// ---------------- Stage 1: pack-2 radix-4 DIF FFT + PHAT -> bf16 unit spectra ------------
// One complex FFT of z = x[2r] + i*x[2r+1] serves two signal rows.
// X0[f] = (Z[f]+conj(Z[-f]))/2,  X1[f] = -i(Z[f]-conj(Z[-f]))/2.
__global__ __launch_bounds__(512) void k_fft_phat(const float* __restrict__ x,
                                                  unsigned short* __restrict__ Xr,
                                                  unsigned short* __restrict__ Xi) {
  __shared__ float re[KLEN + 64];
  __shared__ float im[KLEN + 64];
  const int blk = blockIdx.x;          // handles rows 2*blk, 2*blk+1
  const int tid = threadIdx.x;
  const float* x0 = x + (size_t)(2 * blk) * KLEN;
  const float* x1 = x0 + KLEN;

  // natural-order coalesced load (float4 never crosses a 64-float boundary)
  #pragma unroll
  for (int q = 0; q < 2; q++) {
    int p = tid * 8 + q * 4;
    *(float4*)&re[AP(p)] = ((const float4*)x0)[tid * 2 + q];
    *(float4*)&im[AP(p)] = ((const float4*)x1)[tid * 2 + q];
  }
  __syncthreads();

  // 4 radix-4 DIF stages in LDS: L = 4096, 1024, 256, 64
  #pragma unroll
  for (int s = 0; s < 4; s++) {
    const int lq = 10 - 2 * s;
    const int Q  = 1 << lq;
    const int Qa = Q + (Q >> 6);
    const float wconst = -6.2831853071795864f / (float)(4 << lq);
    #pragma unroll
    for (int it = 0; it < 2; it++) {
      const int u = tid + (it << 9);         // 0..1023
      const int j = u & (Q - 1);
      const int p0 = AP(((u >> lq) << (lq + 2)) + j);
      float x0r = re[p0],          x0i = im[p0];
      float x1r = re[p0 + Qa],     x1i = im[p0 + Qa];
      float x2r = re[p0 + 2 * Qa], x2i = im[p0 + 2 * Qa];
      float x3r = re[p0 + 3 * Qa], x3i = im[p0 + 3 * Qa];
      float s1, c1;
      __sincosf(wconst * (float)j, &s1, &c1);
      float c2 = c1 * c1 - s1 * s1, s2 = 2.f * c1 * s1;
      float c3 = c1 * c2 - s1 * s2, s3 = c1 * s2 + s1 * c2;
      float ar = x0r + x2r, ai = x0i + x2i;
      float br = x0r - x2r, bi = x0i - x2i;
      float cr = x1r + x3r, ci = x1i + x3i;
      float dr = x1r - x3r, di = x1i - x3i;
      float t1r = br + di, t1i = bi - dr;     // (b - i d)
      float t2r = ar - cr, t2i = ai - ci;
      float t3r = br - di, t3i = bi + dr;     // (b + i d)
      re[p0]          = ar + cr;              im[p0]          = ai + ci;
      re[p0 + Qa]     = t1r * c1 - t1i * s1;  im[p0 + Qa]     = t1r * s1 + t1i * c1;
      re[p0 + 2 * Qa] = t2r * c2 - t2i * s2;  im[p0 + 2 * Qa] = t2r * s2 + t2i * c2;
      re[p0 + 3 * Qa] = t3r * c3 - t3i * s3;  im[p0 + 3 * Qa] = t3r * s3 + t3i * c3;
    }
    __syncthreads();
  }

  // fused last two stages (L=16 then L=4) in registers, 16 contiguous points/thread
  if (tid < 256) {
    const int ab = AP(tid << 4);
    float R[16], I[16];
    #pragma unroll
    for (int q = 0; q < 4; q++) {
      *(float4*)&R[q * 4] = *(float4*)&re[ab + q * 4];
      *(float4*)&I[q * 4] = *(float4*)&im[ab + q * 4];
    }
    const float TC[4] = {1.f, 0.92387953251f, 0.70710678119f, 0.38268343236f};
    const float TS[4] = {0.f, -0.38268343236f, -0.70710678119f, -0.92387953251f};
    #pragma unroll
    for (int j = 0; j < 4; j++) {
      float c1 = TC[j], s1 = TS[j];
      float c2 = c1 * c1 - s1 * s1, s2 = 2.f * c1 * s1;
      float c3 = c1 * c2 - s1 * s2, s3 = c1 * s2 + s1 * c2;
      float x0r = R[j],      x0i = I[j];
      float x1r = R[j + 4],  x1i = I[j + 4];
      float x2r = R[j + 8],  x2i = I[j + 8];
      float x3r = R[j + 12], x3i = I[j + 12];
      float ar = x0r + x2r, ai = x0i + x2i;
      float br = x0r - x2r, bi = x0i - x2i;
      float cr = x1r + x3r, ci = x1i + x3i;
      float dr = x1r - x3r, di = x1i - x3i;
      float t1r = br + di, t1i = bi - dr;
      float t2r = ar - cr, t2i = ai - ci;
      float t3r = br - di, t3i = bi + dr;
      R[j]      = ar + cr;             I[j]      = ai + ci;
      R[j + 4]  = t1r * c1 - t1i * s1; I[j + 4]  = t1r * s1 + t1i * c1;
      R[j + 8]  = t2r * c2 - t2i * s2; I[j + 8]  = t2r * s2 + t2i * c2;
      R[j + 12] = t3r * c3 - t3i * s3; I[j + 12] = t3r * s3 + t3i * c3;
    }
    #pragma unroll
    for (int h = 0; h < 4; h++) {
      const int i0 = 4 * h;
      float x0r = R[i0],     x0i = I[i0];
      float x1r = R[i0 + 1], x1i = I[i0 + 1];
      float x2r = R[i0 + 2], x2i = I[i0 + 2];
      float x3r = R[i0 + 3], x3i = I[i0 + 3];
      float ar = x0r + x2r, ai = x0i + x2i;
      float br = x0r - x2r, bi = x0i - x2i;
      float cr = x1r + x3r, ci = x1i + x3i;
      float dr = x1r - x3r, di = x1i - x3i;
      R[i0]     = ar + cr; I[i0]     = ai + ci;
      R[i0 + 1] = br + di; I[i0 + 1] = bi - dr;
      R[i0 + 2] = ar - cr; I[i0 + 2] = ai - ci;
      R[i0 + 3] = br - di; I[i0 + 3] = bi + dr;
    }
    #pragma unroll
    for (int q = 0; q < 4; q++) {
      *(float4*)&re[ab + q * 4] = *(float4*)&R[q * 4];
      *(float4*)&im[ab + q * 4] = *(float4*)&I[q * 4];
    }
  }
  __syncthreads();

  // unpack two rfft spectra + PHAT; gathers are AP-mapped (2 lanes/bank = free)
  unsigned short* Xr0 = Xr + (size_t)(2 * blk) * NFP;
  unsigned short* Xi0 = Xi + (size_t)(2 * blk) * NFP;
  for (int f = tid; f < NFP; f += 512) {
    float a0 = 0.f, b0 = 0.f, a1 = 0.f, b1 = 0.f;
    if (f < NF) {
      int i1 = AP(dr4(f));
      int i2 = AP(dr4((KLEN - f) & (KLEN - 1)));
      float zr = re[i1], zi = im[i1];
      float wr = re[i2], wi = im[i2];
      float X0r = 0.5f * (zr + wr), X0i = 0.5f * (zi - wi);
      float X1r = 0.5f * (zi + wi), X1i = 0.5f * (wr - zr);
      float m0 = sqrtf(X0r * X0r + X0i * X0i) + 1e-12f;
      float m1 = sqrtf(X1r * X1r + X1i * X1i) + 1e-12f;
      a0 = X0r / m0; b0 = X0i / m0;
      a1 = X1r / m1; b1 = X1i / m1;
    }
    Xr0[f]       = f2bf(a0);
    Xi0[f]       = f2bf(b0);
    Xr0[NFP + f] = f2bf(a1);
    Xi0[NFP + f] = f2bf(b1);
  }
}

// ---------------- Stage 2: lag tables, slice-tiled + XOR-swizzled chunk layout ----------
__global__ __launch_bounds__(256) void k_tables(unsigned short* __restrict__ Tbl) {
  int e = blockIdx.x * 256 + threadIdx.x;
  if (e >= 2 * TBLN) return;
  int ph = e / TBLN;
  int r  = e - ph * TBLN;
  int s  = r / (BROWS * 32);
  int r2 = r - s * (BROWS * 32);
  int row = r2 >> 5;
  int q   = r2 & 31;
  int chp = q >> 3;
  int j   = q & 7;
  int chl = chp ^ ((row >> 1) & 3);
  int f   = s * 32 + chl * 8 + j;
  float val = 0.f;
  if (row <= 128 && f <= 2048) {
    float wgt = (f == 0 || f == KLEN / 2) ? (1.0f / KLEN) : (2.0f / KLEN);
    int rr = (f * row) & (KLEN - 1);
    float ang = (float)rr * (6.2831853071795864f / KLEN);
    float sn, cs;
    __sincosf(ang, &sn, &cs);
    val = ph ? (-wgt * sn) : (wgt * cs);
  }
  Tbl[e] = f2bf(val);
}

// ---------------- Stage 3: out = Gr·C + Gi·S, depth-2 counted-vmcnt pipeline -------------
// grid (4, 128): mb = quarter of pairs (36 rows), b. 512 thr = 8 waves (2M x 4N).
// tile M=48 (36 live), N=144 (9 frags), K-step 32, 65 steps. 3 LDS buffers, vmcnt(3).
// Every wave issues EXACTLY 3 global_load_lds per STAGE -> vmcnt(3) == "newest stage
// still in flight, older ones done".
__global__ __launch_bounds__(512, 4) void k_corr(const unsigned short* __restrict__ Xr,
                                                 const unsigned short* __restrict__ Xi,
                                                 const unsigned short* __restrict__ Tbl,
                                                 float* __restrict__ out) {
  extern __shared__ unsigned short smem[];
  unsigned short* SXs = smem + XS_OFF;   // [3][1024]
  unsigned short* SBs = smem + BS_OFF;   // [3][9216] = [3][C 576 chunks | S 576]
  unsigned short* SAs = smem + AS_OFF;   // [2][48*40]

  const int b    = blockIdx.y;
  const int mb   = blockIdx.x;
  const int tid  = threadIdx.x;
  const int w    = tid >> 6;
  const int wm   = w >> 2;            // 0..1
  const int wn   = w & 3;             // 0..3
  const int lane = tid & 63;
  const int arow = lane & 15;
  const int g    = lane >> 4;         // 0..3 (k chunk)
  const int aoff = g << 3;
  const int nmf  = (wm == 0) ? 2 : 1; // M-frags owned by this wave

  floatx4 acc[2][3];
  #pragma unroll
  for (int i = 0; i < 2; i++)
    #pragma unroll
    for (int j = 0; j < 3; j++)
      acc[i][j] = (floatx4){0.f, 0.f, 0.f, 0.f};

  const unsigned short* XrB = Xr + (size_t)b * NSIG * NFP;
  const unsigned short* XiB = Xi + (size_t)b * NSIG * NFP;

  auto bsrc = [&](int cc, size_t so) -> const unsigned short* {
    int tbl = cc >= 576;
    int c = cc - 576 * tbl;
    return Tbl + (size_t)tbl * TBLN + so + (size_t)c * 8;
  };

  auto STAGE = [&](int sl, int nb) {
    unsigned short* Bb = SBs + nb * 9216;
    unsigned short* Xb = SXs + nb * 1024;
    const size_t so = (size_t)sl * 4608;
    const int f0n = sl * 32;
    int cc0 = (w << 6) + lane;
    gload16(bsrc(cc0, so), Bb + (size_t)(w << 6) * 8);
    int cc1 = 512 + cc0;
    gload16(bsrc(cc1, so), Bb + (size_t)(512 + (w << 6)) * 8);
    if (w < 2) {
      int cc2 = 1024 + cc0;
      gload16(bsrc(cc2, so), Bb + (size_t)(1024 + (w << 6)) * 8);
    } else if (w == 2) {           // X chunks 0..63: Xr rows 0..11, Xi rows 0..3
      int part = lane >= 48;
      int cc = lane - part * 48;
      const unsigned short* src = (part ? XiB : XrB) + (cc >> 2) * NFP + f0n + ((cc & 3) << 3);
      gload16(src, Xb);
    } else {                       // w==3: X chunks 64..95: Xi rows 4..11
      if (lane < 32) {
        int cc = 16 + lane;
        gload16(XiB + (cc >> 2) * NFP + f0n + ((cc & 3) << 3), Xb + 512);
      } else {
        // keep per-wave load count uniform at 3: reload first B chunk into its slot
        gload16(bsrc(lane - 32 + 1024, so), Bb + (size_t)(1024 + (lane - 32)) * 8);
      }
    }
  };

  // prologue: stage slices 0,1; wait slice 0 (leave slice 1's 3 loads in flight)
  STAGE(0, 0);
  STAGE(1, 1);
  asm volatile("s_waitcnt vmcnt(3)" ::: "memory");
  __builtin_amdgcn_s_barrier();
  asm volatile("" ::: "memory");

  int bf = 0;
  for (int t = 0; t < NSLICE; t++) {
    const int nb = (bf == 0) ? 2 : bf - 1;        // (bf+2)%3
    if (t + 2 < NSLICE) STAGE(t + 2, nb);

    const unsigned short* Xb = SXs + bf * 1024;
    const unsigned short* Bb = SBs + bf * 9216;

    // A tiles: Gr and Gi share the X loads/unpacks. 48 rows x 16 kk-pairs = 768 items.
    #pragma unroll
    for (int ee = 0; ee < 2; ee++) {
      int e = tid + (ee << 9);        // 0..1023
      if (e < 768) {
        int rl = e >> 4;              // 0..47
        int kk = (e & 15) << 1;
        unsigned pr = 0, pi = 0;
        if (rl < 36) {
          int p = mb * 36 + rl;
          int n = p / 12;
          int m = p - n * 12;
          unsigned urn = *(const unsigned*)(Xb + n * 32 + kk);
          unsigned uin = *(const unsigned*)(Xb + 384 + n * 32 + kk);
          unsigned urm = *(const unsigned*)(Xb + m * 32 + kk);
          unsigned uim = *(const unsigned*)(Xb + 384 + m * 32 + kk);
          float rn0 = ubits(urn << 16), rn1 = ubits(urn & 0xffff0000u);
          float in0 = ubits(uin << 16), in1 = ubits(uin & 0xffff0000u);
          float rm0 = ubits(urm << 16), rm1 = ubits(urm & 0xffff0000u);
          float im0 = ubits(uim << 16), im1 = ubits(uim & 0xffff0000u);
          float vr0 = rn0 * rm0 + in0 * im0, vr1 = rn1 * rm1 + in1 * im1;
          float vi0 = in0 * rm0 - rn0 * im0, vi1 = in1 * rm1 - rn1 * im1;
          pr = (unsigned)f2bf(vr0) | ((unsigned)f2bf(vr1) << 16);
          pi = (unsigned)f2bf(vi0) | ((unsigned)f2bf(vi1) << 16);
        }
        *(unsigned*)(SAs + rl * 40 + kk) = pr;
        *(unsigned*)(SAs + 1920 + rl * 40 + kk) = pi;
      }
    }

    asm volatile("s_waitcnt lgkmcnt(0)" ::: "memory");
    __builtin_amdgcn_s_barrier();
    asm volatile("" ::: "memory");

    short8_t aC[2], aS[2];
    #pragma unroll
    for (int mi = 0; mi < 2; mi++)
      if (mi < nmf) {
        const int ro = (wm * 32 + mi * 16 + arow) * 40 + aoff;
        aC[mi] = *(const short8_t*)(SAs + ro);
        aS[mi] = *(const short8_t*)(SAs + 1920 + ro);
      }
    #pragma unroll
    for (int ni = 0; ni < 3; ni++) {
      const int ct = ni * 4 + wn;
      if (ct <= 8) {
        const int brow = ct * 16 + arow;
        const int chp  = g ^ ((brow >> 1) & 3);   // un-swizzle
        const unsigned short* bp = Bb + brow * 32 + (chp << 3);
        short8_t bC = *(const short8_t*)bp;
        short8_t bS = *(const short8_t*)(bp + 4608);
        #pragma unroll
        for (int mi = 0; mi < 2; mi++)
          if (mi < nmf) {
            acc[mi][ni] = __builtin_amdgcn_mfma_f32_16x16x32_bf16(aC[mi], bC, acc[mi][ni], 0, 0, 0);
            acc[mi][ni] = __builtin_amdgcn_mfma_f32_16x16x32_bf16(aS[mi], bS, acc[mi][ni], 0, 0, 0);
          }
      }
    }

    // end of step: retire stage(t+1) only; keep stage(t+2)'s 3 loads in flight
    if (t + 1 < NSLICE) {
      if (t + 2 < NSLICE) {
        asm volatile("s_waitcnt vmcnt(3)" ::: "memory");
      } else {
        asm volatile("s_waitcnt vmcnt(0)" ::: "memory");
      }
      __builtin_amdgcn_s_barrier();
      asm volatile("" ::: "memory");
    }
    bf = (bf + 1 == 3) ? 0 : bf + 1;
  }

  // epilogue: D col = lane&15 (tau), row = (lane>>4)*4 + reg.
  // direct slot (p, tau) plus mirrored slot (swap(p), 257-tau) for tau>=1.
  const int rbase = g << 2;
  #pragma unroll
  for (int ni = 0; ni < 3; ni++) {
    const int ct = ni * 4 + wn;
    if (ct > 8) continue;
    const int tau = ct * 16 + arow;
    if (tau > 128) continue;
    #pragma unroll
    for (int mi = 0; mi < 2; mi++) {
      if (mi >= nmf) continue;
      #pragma unroll
      for (int r = 0; r < 4; r++) {
        int rl = wm * 32 + mi * 16 + rbase + r;
        if (rl < 36) {
          int p = mb * 36 + rl;
          int n = p / 12;
          int m = p - n * 12;
          float val = acc[mi][ni][r];
          out[((size_t)b * 144 + p) * NTAU + tau] = val;
          if (tau > 0)
            out[((size_t)b * 144 + m * 12 + n) * NTAU + (NTAU - tau)] = val;
        }
      }
    }
  }
}

extern "C" void kernel_launch(void* const* d_in, const int* in_sizes, int n_in,
                              void* d_out, int out_size, void* d_ws, size_t ws_size,
                              hipStream_t stream) {
  const float* x = (const float*)d_in[0];
  float* out = (float*)d_out;

  // ws layout (~13.1 MB): [Tbl 2 phases][Xr][Xi]
  unsigned short* Tbl = (unsigned short*)d_ws;                // 2*TBLN shorts
  unsigned short* Xr  = Tbl + 2 * TBLN;                       // NROW*NFP
  unsigned short* Xi  = Xr + (size_t)NROW * NFP;              // NROW*NFP

  k_fft_phat<<<NROW / 2, 512, 0, stream>>>(x, Xr, Xi);
  k_tables<<<(2 * TBLN + 255) / 256, 256, 0, stream>>>(Tbl);
  k_corr<<<dim3(4, NB), 512, LDS_SHORTS * 2, stream>>>(Xr, Xi, Tbl, out);
}